// Round 5
// baseline (154.111 us; speedup 1.0000x reference)
//
#include <hip/hip_runtime.h>

#define NN 50000
#define NE 800000
#define GEMM_BLOCKS 782      // ceil(50000/64) rows of 64
#define NA_BLOCKS 782        // node_alpha: 64 rows per block
#define HIST_BLOCKS 512
#define SCAN_BLOCKS 49       // ceil(50000/1024)

typedef unsigned short ushort_t;
typedef __attribute__((ext_vector_type(8))) short short8;       // 8 bf16 (4 VGPR) MFMA frag
typedef __attribute__((ext_vector_type(8))) unsigned short u16x8;
typedef __attribute__((ext_vector_type(4))) float f32x4;

__device__ __forceinline__ ushort_t f2bf(float f) {
    unsigned u = __float_as_uint(f);
    unsigned r = (u + 0x7fffu + ((u >> 16) & 1u)) >> 16;   // RNE
    return (ushort_t)r;
}
__device__ __forceinline__ float bf_lo(unsigned u) { return __uint_as_float(u << 16); }
__device__ __forceinline__ float bf_hi(unsigned u) { return __uint_as_float(u & 0xffff0000u); }
__device__ __forceinline__ float lrelu(float v) { return (v > 0.f) ? v : 0.2f * v; }
// LDS XOR swizzle for 256B-stride rows (kills ds_read_b128 bank conflicts)
__device__ __forceinline__ int swz(int b) { return b ^ (((b >> 8) & 7) << 4); }

// ---- K0: prep — Wt bf16 transpose [128][128] + folded logit vectors wa/ba ----
__global__ __launch_bounds__(256) void prep(
    const float* __restrict__ W, const float* __restrict__ bl,
    const float* __restrict__ alpha,
    ushort_t* __restrict__ Wt, float2* __restrict__ wa, float2* __restrict__ ba)
{
    int b = blockIdx.x;
    if (b < 64) {
        int idx = b * 256 + threadIdx.x;       // 16384 = 128*128
        int k = idx >> 7, n = idx & 127;       // coalesced read of W[k][:]
        Wt[n * 128 + k] = f2bf(W[k * 128 + n]);
    } else {
        int t = threadIdx.x;
        if (t < 128) {
            float s0 = 0.f, s1 = 0.f;
            for (int n = 0; n < 64; ++n) {
                s0 += W[t * 128 + n] * alpha[n];
                s1 += W[t * 128 + 64 + n] * alpha[64 + n];
            }
            wa[t] = make_float2(s0, s1);       // logit_h = nodes · wa[:,h] + ba[h]
        } else if (t == 128) {
            float s0 = 0.f, s1 = 0.f;
            for (int n = 0; n < 64; ++n) {
                s0 += bl[n] * alpha[n];
                s1 += bl[64 + n] * alpha[64 + n];
            }
            *ba = make_float2(s0, s1);
        }
    }
}

// ---- K1: fused  MFMA GEMM (Xb = bf16(nodes@W + b)) | exact-fp32 node_alpha | hist
__global__ __launch_bounds__(256) void fused(
    const float* __restrict__ A,      // nodes [NN][128] fp32
    const ushort_t* __restrict__ Wt_g,// bf16 W^T [128][128] (n-major)
    const float* __restrict__ bl,     // [128]
    const float2* __restrict__ wa,    // [128]
    const float2* __restrict__ ba,    // [1]
    const int* __restrict__ rcv,      // [NE]
    ushort_t* __restrict__ Xb,        // bf16 [NN][128]
    float2* __restrict__ a01,         // [NN]
    int* __restrict__ cnt)            // [NN]
{
    __shared__ char lds[49152];       // [0,16K): An 64x128 bf16 ; [16K,48K): Wt 128x128 bf16
    const int bid = blockIdx.x;
    const int t = threadIdx.x;

    if (bid >= GEMM_BLOCKS + NA_BLOCKS) {
        // ---------------- histogram ----------------
        int i = (bid - GEMM_BLOCKS - NA_BLOCKS) * 256 + t;
        for (; i < NE; i += HIST_BLOCKS * 256) atomicAdd(&cnt[rcv[i]], 1);
        return;
    }
    if (bid >= GEMM_BLOCKS) {
        // ------------- node_alpha: exact fp32 logits (64 rows/block) -------------
        const int w = t >> 6, l = t & 63;
        const int base = (bid - GEMM_BLOCKS) * 64 + w * 16;
        float2 wv0 = wa[2 * l], wv1 = wa[2 * l + 1];
        float2 bav = *ba;
        for (int i = 0; i < 16; ++i) {
            int r = base + i;                     // wave-uniform
            if (r >= NN) break;
            float2 v = *(const float2*)(A + (size_t)r * 128 + 2 * l);
            float p0 = v.x * wv0.x + v.y * wv1.x;
            float p1 = v.x * wv0.y + v.y * wv1.y;
#pragma unroll
            for (int d = 1; d < 64; d <<= 1) {
                p0 += __shfl_xor(p0, d);
                p1 += __shfl_xor(p1, d);
            }
            if (l == 0) a01[r] = make_float2(lrelu(p0 + bav.x), lrelu(p1 + bav.y));
        }
        return;
    }

    // ---------------- MFMA GEMM: 64 node-rows x 128 channels ----------------
    const int r0 = bid * 64;
    // stage An (convert fp32 -> bf16), swizzled
#pragma unroll
    for (int it = 0; it < 4; ++it) {
        int id = it * 256 + t;
        int row = id >> 4, seg = id & 15;
        int r = r0 + row;
        float4 v0 = make_float4(0.f, 0.f, 0.f, 0.f), v1 = v0;
        if (r < NN) {
            v0 = *(const float4*)(A + (size_t)r * 128 + seg * 8);
            v1 = *(const float4*)(A + (size_t)r * 128 + seg * 8 + 4);
        }
        u16x8 p;
        p[0] = f2bf(v0.x); p[1] = f2bf(v0.y); p[2] = f2bf(v0.z); p[3] = f2bf(v0.w);
        p[4] = f2bf(v1.x); p[5] = f2bf(v1.y); p[6] = f2bf(v1.z); p[7] = f2bf(v1.w);
        *(u16x8*)(lds + swz(row * 256 + seg * 16)) = p;
    }
    // stage Wt (already bf16), swizzled
#pragma unroll
    for (int it = 0; it < 8; ++it) {
        int id = it * 256 + t;
        int n = id >> 4, seg = id & 15;
        u16x8 p = *(const u16x8*)(Wt_g + n * 128 + seg * 8);
        *(u16x8*)(lds + swz(16384 + n * 256 + seg * 16)) = p;
    }
    __syncthreads();

    const int w = t >> 6, l = t & 63;
    const int lrow = l & 15, lk = l >> 4;
    f32x4 acc[8] = {f32x4{0,0,0,0}, f32x4{0,0,0,0}, f32x4{0,0,0,0}, f32x4{0,0,0,0},
                    f32x4{0,0,0,0}, f32x4{0,0,0,0}, f32x4{0,0,0,0}, f32x4{0,0,0,0}};
#pragma unroll
    for (int kc = 0; kc < 4; ++kc) {
        // B-operand: node rows (N-dim = this wave's 16 rows)
        short8 bfrag = *(short8*)(lds + swz((w * 16 + lrow) * 256 + kc * 64 + lk * 16));
#pragma unroll
        for (int ct = 0; ct < 8; ++ct) {
            // A-operand: Wt rows (M-dim = channels ct*16..+15)
            short8 afrag = *(short8*)(lds + swz(16384 + (ct * 16 + lrow) * 256 + kc * 64 + lk * 16));
            acc[ct] = __builtin_amdgcn_mfma_f32_16x16x32_bf16(afrag, bfrag, acc[ct], 0, 0, 0);
        }
    }
    // D: col(lane&15)=node row, row((lane>>4)*4+reg)=channel -> 4 consecutive channels/lane
    const int r = r0 + w * 16 + lrow;
    if (r < NN) {
#pragma unroll
        for (int ct = 0; ct < 8; ++ct) {
            int c0 = ct * 16 + lk * 4;
            float4 b4 = *(const float4*)(bl + c0);
            ushort4 st;
            st.x = f2bf(acc[ct][0] + b4.x);
            st.y = f2bf(acc[ct][1] + b4.y);
            st.z = f2bf(acc[ct][2] + b4.z);
            st.w = f2bf(acc[ct][3] + b4.w);
            *(ushort4*)(Xb + (size_t)r * 128 + c0) = st;
        }
    }
}

// ---- K2a: block-local exclusive scan (49 blocks x 1024, coalesced) ----------
__global__ __launch_bounds__(1024) void scan_partial(
    const int* __restrict__ cnt, int* __restrict__ off, int* __restrict__ bsum)
{
    __shared__ int wsum[16];
    const int t = threadIdx.x, lane = t & 63, wid = t >> 6;
    const int i = blockIdx.x * 1024 + t;
    int v = (i < NN) ? cnt[i] : 0;
    int incl = v;
#pragma unroll
    for (int d = 1; d < 64; d <<= 1) {
        int u = __shfl_up(incl, d);
        if (lane >= d) incl += u;
    }
    if (lane == 63) wsum[wid] = incl;
    __syncthreads();
    if (t < 16) {
        int w = wsum[t], wi = w;
#pragma unroll
        for (int d = 1; d < 16; d <<= 1) {
            int u = __shfl_up(wi, d);
            if (t >= d) wi += u;
        }
        wsum[t] = wi - w;
    }
    __syncthreads();
    int ex = wsum[wid] + (incl - v);
    if (i < NN) off[i] = ex;
    if (t == 1023) bsum[blockIdx.x] = ex + v;
}

// ---- K2b: scan the 49 block totals (one wave) -------------------------------
__global__ __launch_bounds__(64) void scan_mid(int* __restrict__ bsum, int* __restrict__ boff,
                                               int* __restrict__ off)
{
    const int t = threadIdx.x;
    int v = (t < SCAN_BLOCKS) ? bsum[t] : 0;
    int incl = v;
#pragma unroll
    for (int d = 1; d < 64; d <<= 1) {
        int u = __shfl_up(incl, d);
        if (t >= d) incl += u;
    }
    if (t < SCAN_BLOCKS) boff[t] = incl - v;
    if (t == 0) off[NN] = NE;
}

// ---- K2c: add block offsets; seed cnt as the scatter cursor (= off) ---------
__global__ __launch_bounds__(1024) void scan_add(
    int* __restrict__ off, const int* __restrict__ boff, int* __restrict__ cnt)
{
    const int i = blockIdx.x * 1024 + threadIdx.x;
    if (i < NN) {
        int o = off[i] + boff[blockIdx.x];
        off[i] = o;
        cnt[i] = o;
    }
}

// ---- K3: scatter sender ids into CSR order (cur holds absolute positions) ---
__global__ __launch_bounds__(256) void scatter(
    const int* __restrict__ snd, const int* __restrict__ rcv,
    int* __restrict__ cur, int* __restrict__ srt)
{
    int i = blockIdx.x * 256 + threadIdx.x;
    if (i >= NE) return;
    int p = atomicAdd(&cur[rcv[i]], 1);
    srt[p] = snd[i];
}

// ---- K4: per-node aggregation, 4 edges per wave-iteration -------------------
__global__ __launch_bounds__(256) void aggregate(
    const ushort_t* __restrict__ Xb, const float2* __restrict__ a01,
    const int* __restrict__ off, const int* __restrict__ srt,
    const float* __restrict__ bias, float* __restrict__ out)
{
    const int n = blockIdx.x * 4 + (threadIdx.x >> 6);
    const int lane = threadIdx.x & 63;
    const int sub = lane >> 4;
    const int l16 = lane & 15;
    const int head = l16 >> 2;
    const bool soft = (head < 2);
    const int beg = off[n];
    const int deg = off[n + 1] - beg;
    const int total = deg + 1;               // + self loop

    float acc0 = 0.f, acc1 = 0.f, acc2 = 0.f, acc3 = 0.f;
    float acc4 = 0.f, acc5 = 0.f, acc6 = 0.f, acc7 = 0.f;
    float D = 0.f;

    for (int base = 0; base < total; base += 64) {
        int idx = base + lane;
        int sj = (idx < deg) ? srt[beg + idx] : n;
        float2 w2 = a01[sj];
        int cnt4 = min(64, total - base);
        int iters = (cnt4 + 3) >> 2;
#pragma unroll 2
        for (int d = 0; d < iters; ++d) {
            int e = 4 * d + sub;
            bool act = (e < cnt4);
            int   s   = __shfl(sj, e);
            float a0v = __shfl(w2.x, e);
            float a1v = __shfl(w2.y, e);
            float av  = (head == 0) ? a0v : a1v;
            float w   = act ? (soft ? __expf(av) : 1.0f) : 0.0f;
            D += w;
            uint4 u = *(const uint4*)(Xb + (size_t)s * 128 + l16 * 8);
            acc0 = fmaf(w, bf_lo(u.x), acc0);
            acc1 = fmaf(w, bf_hi(u.x), acc1);
            acc2 = fmaf(w, bf_lo(u.y), acc2);
            acc3 = fmaf(w, bf_hi(u.y), acc3);
            acc4 = fmaf(w, bf_lo(u.z), acc4);
            acc5 = fmaf(w, bf_hi(u.z), acc5);
            acc6 = fmaf(w, bf_lo(u.w), acc6);
            acc7 = fmaf(w, bf_hi(u.w), acc7);
        }
    }

    acc0 += __shfl_xor(acc0, 16); acc0 += __shfl_xor(acc0, 32);
    acc1 += __shfl_xor(acc1, 16); acc1 += __shfl_xor(acc1, 32);
    acc2 += __shfl_xor(acc2, 16); acc2 += __shfl_xor(acc2, 32);
    acc3 += __shfl_xor(acc3, 16); acc3 += __shfl_xor(acc3, 32);
    acc4 += __shfl_xor(acc4, 16); acc4 += __shfl_xor(acc4, 32);
    acc5 += __shfl_xor(acc5, 16); acc5 += __shfl_xor(acc5, 32);
    acc6 += __shfl_xor(acc6, 16); acc6 += __shfl_xor(acc6, 32);
    acc7 += __shfl_xor(acc7, 16); acc7 += __shfl_xor(acc7, 32);
    D    += __shfl_xor(D, 16);    D    += __shfl_xor(D, 32);

    if (sub == 0) {
        float scale = soft ? (1.0f / D) : (1.0f / (float)total);
        float4 b0 = *(const float4*)(bias + l16 * 8);
        float4 b1 = *(const float4*)(bias + l16 * 8 + 4);
        float4 o0 = make_float4(acc0 * scale + b0.x, acc1 * scale + b0.y,
                                acc2 * scale + b0.z, acc3 * scale + b0.w);
        float4 o1 = make_float4(acc4 * scale + b1.x, acc5 * scale + b1.y,
                                acc6 * scale + b1.z, acc7 * scale + b1.w);
        *(float4*)(out + (size_t)n * 128 + l16 * 8)     = o0;
        *(float4*)(out + (size_t)n * 128 + l16 * 8 + 4) = o1;
    }
}

// ------------------------------------------------------------------------------
extern "C" void kernel_launch(void* const* d_in, const int* in_sizes, int n_in,
                              void* d_out, int out_size, void* d_ws, size_t ws_size,
                              hipStream_t stream)
{
    const float* nodes     = (const float*)d_in[0];
    const int*   senders   = (const int*)d_in[1];
    const int*   receivers = (const int*)d_in[2];
    const float* W         = (const float*)d_in[3];
    const float* b_lin     = (const float*)d_in[4];
    const float* alpha     = (const float*)d_in[5];
    const float* bias      = (const float*)d_in[6];
    float* out = (float*)d_out;

    char* ws = (char*)d_ws;
    ushort_t* Xb   = (ushort_t*)(ws);               // 12,800,000 B
    float2*   a01  = (float2*)  (ws + 12800000);    //    400,000 B
    int*      cnt  = (int*)     (ws + 13200000);    //    200,000 B
    int*      off  = (int*)     (ws + 13400000);    //    200,064 B (padded)
    int*      srt  = (int*)     (ws + 13600064);    //  3,200,000 B
    int*      bsum = (int*)     (ws + 16800064);    //        256 B
    int*      boff = (int*)     (ws + 16800320);    //        256 B
    // Wt/wa/ba live in the srt region: dead before scatter writes srt (disjoint lifetime)
    ushort_t* Wt_g = (ushort_t*)(ws + 13600064);    //     32,768 B
    float2*   wa   = (float2*)  (ws + 13632832);    //      1,024 B
    float2*   ba   = (float2*)  (ws + 13633856);    //          8 B

    hipMemsetAsync(cnt, 0, NN * sizeof(int), stream);
    prep <<<65, 256, 0, stream>>>(W, b_lin, alpha, Wt_g, wa, ba);
    fused<<<GEMM_BLOCKS + NA_BLOCKS + HIST_BLOCKS, 256, 0, stream>>>(
        nodes, Wt_g, b_lin, wa, ba, receivers, Xb, a01, cnt);
    scan_partial<<<SCAN_BLOCKS, 1024, 0, stream>>>(cnt, off, bsum);
    scan_mid    <<<1, 64, 0, stream>>>(bsum, boff, off);
    scan_add    <<<SCAN_BLOCKS, 1024, 0, stream>>>(off, boff, cnt);
    scatter  <<<(NE + 255) / 256, 256, 0, stream>>>(senders, receivers, cnt, srt);
    aggregate<<<(NN + 3) / 4, 256, 0, stream>>>(Xb, a01, off, srt, bias, out);
}

// Round 6
// 146.894 us; speedup vs baseline: 1.0491x; 1.0491x over previous
//
#include <hip/hip_runtime.h>

#define NN 50000
#define NE 800000
#define GEMM_BLOCKS 782      // ceil(50000/64) rows of 64
#define HIST_BLOCKS 512
#define SCAN_BLOCKS 49       // ceil(50000/1024)

typedef unsigned short ushort_t;
typedef __attribute__((ext_vector_type(8))) short short8;       // 8 bf16 (4 VGPR) MFMA frag
typedef __attribute__((ext_vector_type(8))) unsigned short u16x8;
typedef __attribute__((ext_vector_type(4))) float f32x4;

__device__ __forceinline__ ushort_t f2bf(float f) {
    unsigned u = __float_as_uint(f);
    unsigned r = (u + 0x7fffu + ((u >> 16) & 1u)) >> 16;   // RNE
    return (ushort_t)r;
}
__device__ __forceinline__ float bf_lo(unsigned u) { return __uint_as_float(u << 16); }
__device__ __forceinline__ float bf_hi(unsigned u) { return __uint_as_float(u & 0xffff0000u); }
__device__ __forceinline__ float lrelu(float v) { return (v > 0.f) ? v : 0.2f * v; }
// LDS XOR swizzle for 256B-stride rows (kills ds_read_b128 bank conflicts)
__device__ __forceinline__ int swz(int b) { return b ^ (((b >> 8) & 7) << 4); }

// ---- K0: prep — Wt bf16 transpose [128][128] + folded logit vectors wa/ba ----
__global__ __launch_bounds__(256) void prep(
    const float* __restrict__ W, const float* __restrict__ bl,
    const float* __restrict__ alpha,
    ushort_t* __restrict__ Wt, float2* __restrict__ wa, float2* __restrict__ ba)
{
    int b = blockIdx.x;
    if (b < 64) {
        int idx = b * 256 + threadIdx.x;       // 16384 = 128*128
        int k = idx >> 7, n = idx & 127;       // coalesced read of W[k][:]
        Wt[n * 128 + k] = f2bf(W[k * 128 + n]);
    } else {
        int t = threadIdx.x;
        if (t < 128) {
            float s0 = 0.f, s1 = 0.f;
            for (int n = 0; n < 64; ++n) {
                s0 += W[t * 128 + n] * alpha[n];
                s1 += W[t * 128 + 64 + n] * alpha[64 + n];
            }
            wa[t] = make_float2(s0, s1);       // logit_h = nodes · wa[:,h] + ba[h]
        } else if (t == 128) {
            float s0 = 0.f, s1 = 0.f;
            for (int n = 0; n < 64; ++n) {
                s0 += bl[n] * alpha[n];
                s1 += bl[64 + n] * alpha[64 + n];
            }
            *ba = make_float2(s0, s1);
        }
    }
}

// ---- K1: fused  MFMA GEMM (Xb = bf16(nodes@W + b)) + fp32 a01-during-staging + hist
__global__ __launch_bounds__(256) void fused(
    const float* __restrict__ A,      // nodes [NN][128] fp32
    const ushort_t* __restrict__ Wt_g,// bf16 W^T [128][128] (n-major)
    const float* __restrict__ bl,     // [128]
    const float2* __restrict__ wa,    // [128]
    const float2* __restrict__ ba,    // [1]
    const int* __restrict__ rcv,      // [NE]
    ushort_t* __restrict__ Xb,        // bf16 [NN][128]
    float2* __restrict__ a01,         // [NN]
    int* __restrict__ cnt)            // [NN]
{
    __shared__ char lds[49152];       // [0,16K): An 64x128 bf16 ; [16K,48K): Wt 128x128 bf16
    const int bid = blockIdx.x;
    const int t = threadIdx.x;

    if (bid >= GEMM_BLOCKS) {
        // ---------------- histogram ----------------
        int i = (bid - GEMM_BLOCKS) * 256 + t;
        for (; i < NE; i += HIST_BLOCKS * 256) atomicAdd(&cnt[rcv[i]], 1);
        return;
    }

    // ---------------- MFMA GEMM: 64 node-rows x 128 channels ----------------
    const int r0 = bid * 64;
    const int seg = t & 15;                 // k-segment (8 fp32) — constant per thread
    float2 wv[8];
#pragma unroll
    for (int j = 0; j < 8; ++j) wv[j] = wa[seg * 8 + j];
    const float2 bav = *ba;

    // stage An (fp32 -> bf16, swizzled) and compute exact-fp32 logits on the fly
#pragma unroll
    for (int it = 0; it < 4; ++it) {
        int row = it * 16 + (t >> 4);
        int r = r0 + row;
        float4 v0 = make_float4(0.f, 0.f, 0.f, 0.f), v1 = v0;
        if (r < NN) {
            v0 = *(const float4*)(A + (size_t)r * 128 + seg * 8);
            v1 = *(const float4*)(A + (size_t)r * 128 + seg * 8 + 4);
        }
        u16x8 p;
        p[0] = f2bf(v0.x); p[1] = f2bf(v0.y); p[2] = f2bf(v0.z); p[3] = f2bf(v0.w);
        p[4] = f2bf(v1.x); p[5] = f2bf(v1.y); p[6] = f2bf(v1.z); p[7] = f2bf(v1.w);
        *(u16x8*)(lds + swz(row * 256 + seg * 16)) = p;
        // logit partials: k = seg*8 + j
        float p0 = v0.x * wv[0].x + v0.y * wv[1].x + v0.z * wv[2].x + v0.w * wv[3].x
                 + v1.x * wv[4].x + v1.y * wv[5].x + v1.z * wv[6].x + v1.w * wv[7].x;
        float p1 = v0.x * wv[0].y + v0.y * wv[1].y + v0.z * wv[2].y + v0.w * wv[3].y
                 + v1.x * wv[4].y + v1.y * wv[5].y + v1.z * wv[6].y + v1.w * wv[7].y;
#pragma unroll
        for (int d = 1; d < 16; d <<= 1) {
            p0 += __shfl_xor(p0, d);
            p1 += __shfl_xor(p1, d);
        }
        if (seg == 0 && r < NN)
            a01[r] = make_float2(lrelu(p0 + bav.x), lrelu(p1 + bav.y));
    }
    // stage Wt (already bf16), swizzled
#pragma unroll
    for (int it = 0; it < 8; ++it) {
        int id = it * 256 + t;
        int n = id >> 4, sg = id & 15;
        u16x8 p = *(const u16x8*)(Wt_g + n * 128 + sg * 8);
        *(u16x8*)(lds + swz(16384 + n * 256 + sg * 16)) = p;
    }
    __syncthreads();

    const int w = t >> 6, l = t & 63;
    const int lrow = l & 15, lk = l >> 4;
    f32x4 acc[8] = {f32x4{0,0,0,0}, f32x4{0,0,0,0}, f32x4{0,0,0,0}, f32x4{0,0,0,0},
                    f32x4{0,0,0,0}, f32x4{0,0,0,0}, f32x4{0,0,0,0}, f32x4{0,0,0,0}};
#pragma unroll
    for (int kc = 0; kc < 4; ++kc) {
        // B-operand: node rows (N-dim = this wave's 16 rows)
        short8 bfrag = *(short8*)(lds + swz((w * 16 + lrow) * 256 + kc * 64 + lk * 16));
#pragma unroll
        for (int ct = 0; ct < 8; ++ct) {
            // A-operand: Wt rows (M-dim = channels ct*16..+15)
            short8 afrag = *(short8*)(lds + swz(16384 + (ct * 16 + lrow) * 256 + kc * 64 + lk * 16));
            acc[ct] = __builtin_amdgcn_mfma_f32_16x16x32_bf16(afrag, bfrag, acc[ct], 0, 0, 0);
        }
    }
    // D: col(lane&15)=node row, row((lane>>4)*4+reg)=channel -> 4 consecutive channels/lane
    const int r = r0 + w * 16 + lrow;
    if (r < NN) {
#pragma unroll
        for (int ct = 0; ct < 8; ++ct) {
            int c0 = ct * 16 + lk * 4;
            float4 b4 = *(const float4*)(bl + c0);
            ushort4 st;
            st.x = f2bf(acc[ct][0] + b4.x);
            st.y = f2bf(acc[ct][1] + b4.y);
            st.z = f2bf(acc[ct][2] + b4.z);
            st.w = f2bf(acc[ct][3] + b4.w);
            *(ushort4*)(Xb + (size_t)r * 128 + c0) = st;
        }
    }
}

// ---- K2a: block-local exclusive scan (49 blocks x 1024, coalesced) ----------
__global__ __launch_bounds__(1024) void scan_partial(
    const int* __restrict__ cnt, int* __restrict__ off, int* __restrict__ bsum)
{
    __shared__ int wsum[16];
    const int t = threadIdx.x, lane = t & 63, wid = t >> 6;
    const int i = blockIdx.x * 1024 + t;
    int v = (i < NN) ? cnt[i] : 0;
    int incl = v;
#pragma unroll
    for (int d = 1; d < 64; d <<= 1) {
        int u = __shfl_up(incl, d);
        if (lane >= d) incl += u;
    }
    if (lane == 63) wsum[wid] = incl;
    __syncthreads();
    if (t < 16) {
        int w = wsum[t], wi = w;
#pragma unroll
        for (int d = 1; d < 16; d <<= 1) {
            int u = __shfl_up(wi, d);
            if (t >= d) wi += u;
        }
        wsum[t] = wi - w;
    }
    __syncthreads();
    int ex = wsum[wid] + (incl - v);
    if (i < NN) off[i] = ex;
    if (t == 1023) bsum[blockIdx.x] = ex + v;
}

// ---- K2b: scan the 49 block totals (one wave) -------------------------------
__global__ __launch_bounds__(64) void scan_mid(int* __restrict__ bsum, int* __restrict__ boff,
                                               int* __restrict__ off)
{
    const int t = threadIdx.x;
    int v = (t < SCAN_BLOCKS) ? bsum[t] : 0;
    int incl = v;
#pragma unroll
    for (int d = 1; d < 64; d <<= 1) {
        int u = __shfl_up(incl, d);
        if (t >= d) incl += u;
    }
    if (t < SCAN_BLOCKS) boff[t] = incl - v;
    if (t == 0) off[NN] = NE;
}

// ---- K2c: add block offsets; seed cnt as the scatter cursor (= off) ---------
__global__ __launch_bounds__(1024) void scan_add(
    int* __restrict__ off, const int* __restrict__ boff, int* __restrict__ cnt)
{
    const int i = blockIdx.x * 1024 + threadIdx.x;
    if (i < NN) {
        int o = off[i] + boff[blockIdx.x];
        off[i] = o;
        cnt[i] = o;
    }
}

// ---- K3: scatter sender ids into CSR order (cur holds absolute positions) ---
__global__ __launch_bounds__(256) void scatter(
    const int* __restrict__ snd, const int* __restrict__ rcv,
    int* __restrict__ cur, int* __restrict__ srt)
{
    int i = blockIdx.x * 256 + threadIdx.x;
    if (i >= NE) return;
    int p = atomicAdd(&cur[rcv[i]], 1);
    srt[p] = snd[i];
}

// ---- K4: per-node aggregation, 4 edges per wave-iteration -------------------
__global__ __launch_bounds__(256) void aggregate(
    const ushort_t* __restrict__ Xb, const float2* __restrict__ a01,
    const int* __restrict__ off, const int* __restrict__ srt,
    const float* __restrict__ bias, float* __restrict__ out)
{
    const int n = blockIdx.x * 4 + (threadIdx.x >> 6);
    const int lane = threadIdx.x & 63;
    const int sub = lane >> 4;
    const int l16 = lane & 15;
    const int head = l16 >> 2;
    const bool soft = (head < 2);
    const int beg = off[n];
    const int deg = off[n + 1] - beg;
    const int total = deg + 1;               // + self loop

    float acc0 = 0.f, acc1 = 0.f, acc2 = 0.f, acc3 = 0.f;
    float acc4 = 0.f, acc5 = 0.f, acc6 = 0.f, acc7 = 0.f;
    float D = 0.f;

    for (int base = 0; base < total; base += 64) {
        int idx = base + lane;
        int sj = (idx < deg) ? srt[beg + idx] : n;
        float2 w2 = a01[sj];
        int cnt4 = min(64, total - base);
        int iters = (cnt4 + 3) >> 2;
#pragma unroll 2
        for (int d = 0; d < iters; ++d) {
            int e = 4 * d + sub;
            bool act = (e < cnt4);
            int   s   = __shfl(sj, e);
            float a0v = __shfl(w2.x, e);
            float a1v = __shfl(w2.y, e);
            float av  = (head == 0) ? a0v : a1v;
            float w   = act ? (soft ? __expf(av) : 1.0f) : 0.0f;
            D += w;
            uint4 u = *(const uint4*)(Xb + (size_t)s * 128 + l16 * 8);
            acc0 = fmaf(w, bf_lo(u.x), acc0);
            acc1 = fmaf(w, bf_hi(u.x), acc1);
            acc2 = fmaf(w, bf_lo(u.y), acc2);
            acc3 = fmaf(w, bf_hi(u.y), acc3);
            acc4 = fmaf(w, bf_lo(u.z), acc4);
            acc5 = fmaf(w, bf_hi(u.z), acc5);
            acc6 = fmaf(w, bf_lo(u.w), acc6);
            acc7 = fmaf(w, bf_hi(u.w), acc7);
        }
    }

    acc0 += __shfl_xor(acc0, 16); acc0 += __shfl_xor(acc0, 32);
    acc1 += __shfl_xor(acc1, 16); acc1 += __shfl_xor(acc1, 32);
    acc2 += __shfl_xor(acc2, 16); acc2 += __shfl_xor(acc2, 32);
    acc3 += __shfl_xor(acc3, 16); acc3 += __shfl_xor(acc3, 32);
    acc4 += __shfl_xor(acc4, 16); acc4 += __shfl_xor(acc4, 32);
    acc5 += __shfl_xor(acc5, 16); acc5 += __shfl_xor(acc5, 32);
    acc6 += __shfl_xor(acc6, 16); acc6 += __shfl_xor(acc6, 32);
    acc7 += __shfl_xor(acc7, 16); acc7 += __shfl_xor(acc7, 32);
    D    += __shfl_xor(D, 16);    D    += __shfl_xor(D, 32);

    if (sub == 0) {
        float scale = soft ? (1.0f / D) : (1.0f / (float)total);
        float4 b0 = *(const float4*)(bias + l16 * 8);
        float4 b1 = *(const float4*)(bias + l16 * 8 + 4);
        float4 o0 = make_float4(acc0 * scale + b0.x, acc1 * scale + b0.y,
                                acc2 * scale + b0.z, acc3 * scale + b0.w);
        float4 o1 = make_float4(acc4 * scale + b1.x, acc5 * scale + b1.y,
                                acc6 * scale + b1.z, acc7 * scale + b1.w);
        *(float4*)(out + (size_t)n * 128 + l16 * 8)     = o0;
        *(float4*)(out + (size_t)n * 128 + l16 * 8 + 4) = o1;
    }
}

// ------------------------------------------------------------------------------
extern "C" void kernel_launch(void* const* d_in, const int* in_sizes, int n_in,
                              void* d_out, int out_size, void* d_ws, size_t ws_size,
                              hipStream_t stream)
{
    const float* nodes     = (const float*)d_in[0];
    const int*   senders   = (const int*)d_in[1];
    const int*   receivers = (const int*)d_in[2];
    const float* W         = (const float*)d_in[3];
    const float* b_lin     = (const float*)d_in[4];
    const float* alpha     = (const float*)d_in[5];
    const float* bias      = (const float*)d_in[6];
    float* out = (float*)d_out;

    char* ws = (char*)d_ws;
    ushort_t* Xb   = (ushort_t*)(ws);               // 12,800,000 B
    float2*   a01  = (float2*)  (ws + 12800000);    //    400,000 B
    int*      cnt  = (int*)     (ws + 13200000);    //    200,000 B
    int*      off  = (int*)     (ws + 13400000);    //    200,064 B (padded)
    int*      srt  = (int*)     (ws + 13600064);    //  3,200,000 B
    int*      bsum = (int*)     (ws + 16800064);    //        256 B
    int*      boff = (int*)     (ws + 16800320);    //        256 B
    // Wt/wa/ba live in the srt region: dead before scatter writes srt (disjoint lifetime)
    ushort_t* Wt_g = (ushort_t*)(ws + 13600064);    //     32,768 B
    float2*   wa   = (float2*)  (ws + 13632832);    //      1,024 B
    float2*   ba   = (float2*)  (ws + 13633856);    //          8 B

    hipMemsetAsync(cnt, 0, NN * sizeof(int), stream);
    prep <<<65, 256, 0, stream>>>(W, b_lin, alpha, Wt_g, wa, ba);
    fused<<<GEMM_BLOCKS + HIST_BLOCKS, 256, 0, stream>>>(
        nodes, Wt_g, b_lin, wa, ba, receivers, Xb, a01, cnt);
    scan_partial<<<SCAN_BLOCKS, 1024, 0, stream>>>(cnt, off, bsum);
    scan_mid    <<<1, 64, 0, stream>>>(bsum, boff, off);
    scan_add    <<<SCAN_BLOCKS, 1024, 0, stream>>>(off, boff, cnt);
    scatter  <<<(NE + 255) / 256, 256, 0, stream>>>(senders, receivers, cnt, srt);
    aggregate<<<(NN + 3) / 4, 256, 0, stream>>>(Xb, a01, off, srt, bias, out);
}